// Round 12
// baseline (77.171 us; speedup 1.0000x reference)
//
#include <hip/hip_runtime.h>

#define NELL 9
#define CCH  128
#define DB   3
#define P3A  5
#define P2A  3
#define P1A  1
#define P3B  5
#define P2B  2
#define P1B  1
#define NT3  165
#define NT2  45
#define TTOT (NT3 + NT2 + NELL)   // 219 monomials
#define NCGRP 32                  // c-groups per chunk (128 c / 4 waves)

// ws int-region layout (ints): [0..3]=hdr (0:nchunks), [4 .. 4+MAXCH) chunk_e,
// [4+MAXCH .. 4+2*MAXCH) chunk_base, [4+2*MAXCH .. 4+3*MAXCH) chunk_len,
// [4+3*MAXCH .. 4+3*MAXCH+B) perm. Then (256-aligned) the float table.

// ---------------------------------------------------------------------------
// Grouping + chunk build: perm sorted by e; padded 64-row chunks per class.
// Output values are independent of intra-class order (each row's result
// depends only on its own data; each row processed exactly once).
// ---------------------------------------------------------------------------
__global__ __launch_bounds__(1024)
void sc_group(const float* __restrict__ y, int B, int E, int MAXCH,
              int* __restrict__ wsi)
{
    __shared__ int cnt[1024];
    __shared__ int off[1024];
    int* chunk_e    = wsi + 4;
    int* chunk_base = wsi + 4 + MAXCH;
    int* chunk_len  = wsi + 4 + 2 * MAXCH;
    int* perm       = wsi + 4 + 3 * MAXCH;

    for (int i = threadIdx.x; i < E; i += blockDim.x) cnt[i] = 0;
    __syncthreads();
    for (int b = threadIdx.x; b < B; b += blockDim.x) {
        int e = 0;
        for (int q = 0; q < E; q++) if (y[b * E + q] > 0.5f) e = q;
        atomicAdd(&cnt[e], 1);
    }
    __syncthreads();
    if (threadIdx.x == 0) {
        int s = 0;
        for (int e = 0; e < E; e++) { off[e] = s; s += cnt[e]; }
        int nch = 0;
        for (int e = 0; e < E; e++) {
            for (int i = 0; i < cnt[e]; i += 64) {
                chunk_e[nch]    = e;
                chunk_base[nch] = off[e] + i;
                chunk_len[nch]  = (cnt[e] - i < 64) ? (cnt[e] - i) : 64;
                nch++;
            }
        }
        wsi[0] = nch;
    }
    __syncthreads();
    for (int i = threadIdx.x; i < E; i += blockDim.x) cnt[i] = 0;
    __syncthreads();
    for (int b = threadIdx.x; b < B; b += blockDim.x) {
        int e = 0;
        for (int q = 0; q < E; q++) if (y[b * E + q] > 0.5f) e = q;
        int r = atomicAdd(&cnt[e], 1);
        perm[off[e] + r] = b;
    }
}

// ---------------------------------------------------------------------------
// Prep (r7-proven): fused coefficient table, layout [e][t][c] float4 over d.
// ---------------------------------------------------------------------------
__global__ __launch_bounds__(CCH)
void sc_prep(const float* __restrict__ U3a, const float* __restrict__ U2a,
             const float* __restrict__ U1a, const float* __restrict__ U3b,
             const float* __restrict__ U2b, const float* __restrict__ U1b,
             const float* __restrict__ W3a, const float* __restrict__ W2a,
             const float* __restrict__ W1a, const float* __restrict__ W3b,
             const float* __restrict__ W2b, const float* __restrict__ W1b,
             float* __restrict__ tab)
{
    const int bt = blockIdx.x;
    const int e = bt / TTOT, t = bt % TTOT;
    const int c = threadIdx.x;

    float v[4] = {0.f, 0.f, 0.f, 0.f};

    if (t < NT3) {
        int idx = t, i = 0, j = 0, k = 0;
        bool done = false;
        for (i = 0; i < NELL && !done; i++)
            for (j = i; j < NELL && !done; j++)
                for (k = j; k < NELL; k++) {
                    if (idx == 0) { done = true; break; }
                    idx--;
                }
        i--; j--;
        const float mult = (i == k) ? 1.f : ((i == j || j == k) ? 3.f : 6.f);
        const int ijk = (i * 9 + j) * 9 + k;
        for (int p = 0; p < P3A; p++)
            v[0] += U3a[ijk * P3A + p] * W3a[(e * P3A + p) * CCH + c];
        for (int d = 0; d < DB; d++)
            for (int p = 0; p < P3B; p++)
                v[1 + d] += U3b[(d * 729 + ijk) * P3B + p] * W3b[(e * P3B + p) * CCH + c];
        for (int d = 0; d < 4; d++) v[d] *= mult;
    } else if (t < NT3 + NT2) {
        int idx = t - NT3, i = 0, j = 0;
        bool done = false;
        for (i = 0; i < NELL && !done; i++)
            for (j = i; j < NELL; j++) {
                if (idx == 0) { done = true; break; }
                idx--;
            }
        i--;
        const float mult = (i == j) ? 1.f : 2.f;
        const int ij = i * 9 + j;
        for (int p = 0; p < P2A; p++)
            v[0] += U2a[ij * P2A + p] * W2a[(e * P2A + p) * CCH + c];
        for (int d = 0; d < DB; d++)
            for (int p = 0; p < P2B; p++)
                v[1 + d] += U2b[(d * 81 + ij) * P2B + p] * W2b[(e * P2B + p) * CCH + c];
        for (int d = 0; d < 4; d++) v[d] *= mult;
    } else {
        const int i = t - NT3 - NT2;
        v[0] = U1a[i] * W1a[e * CCH + c];
        for (int d = 0; d < DB; d++)
            v[1 + d] = U1b[d * 9 + i] * W1b[e * CCH + c];
    }

    ((float4*)tab)[(size_t)bt * CCH + c] = make_float4(v[0], v[1], v[2], v[3]);
}

// ---------------------------------------------------------------------------
// Chunked main: lane = batch row, (e,c) wave-uniform -> table reads are
// scalar/broadcast (3.5 KB per wave total). Per-row FMA order = r7 verbatim.
// Block = 256 thr = 4 waves; wave w covers c = cgrp*4 + w; chunk = bid/NCGRP.
// ---------------------------------------------------------------------------
__global__ __launch_bounds__(256)
void sc_main_chunk(const float* __restrict__ x, const int* __restrict__ wsi,
                   int MAXCH, const float* __restrict__ tab,
                   float* __restrict__ out)
{
    const int chunk = blockIdx.x / NCGRP;
    const int cgrp  = blockIdx.x % NCGRP;
    const int wave  = threadIdx.x >> 6;
    const int lane  = threadIdx.x & 63;

    const int nch = wsi[0];
    if (chunk >= nch) return;

    const int e    = wsi[4 + chunk];
    const int base = wsi[4 + MAXCH + chunk];
    const int len  = wsi[4 + 2 * MAXCH + chunk];
    const int* perm = wsi + 4 + 3 * MAXCH;

    const int c = __builtin_amdgcn_readfirstlane(cgrp * 4 + wave);

    const bool valid = (lane < len);
    const int slot = base + (valid ? lane : 0);
    const int b = perm[slot];

    float xv[NELL];
    const float* xp = x + ((size_t)b * CCH + c) * NELL;
#pragma unroll
    for (int i = 0; i < NELL; i++) xv[i] = xp[i];

    // wave-uniform coefficient stream (scalar loads)
    const float4* cp = (const float4*)tab +
                       ((size_t)__builtin_amdgcn_readfirstlane(e) * TTOT * CCH + c);

    float4 A = make_float4(0.f, 0.f, 0.f, 0.f);
    int t = 0;
#pragma unroll
    for (int i = 0; i < NELL; i++)
#pragma unroll
        for (int j = i; j < NELL; j++) {
            const float pij = xv[i] * xv[j];
#pragma unroll
            for (int k = j; k < NELL; k++) {
                const float m = pij * xv[k];
                const float4 w = cp[(t++) * CCH];
                A.x = fmaf(w.x, m, A.x);
                A.y = fmaf(w.y, m, A.y);
                A.z = fmaf(w.z, m, A.z);
                A.w = fmaf(w.w, m, A.w);
            }
        }
#pragma unroll
    for (int i = 0; i < NELL; i++)
#pragma unroll
        for (int j = i; j < NELL; j++) {
            const float pij = xv[i] * xv[j];
            const float4 w = cp[(t++) * CCH];
            A.x = fmaf(w.x, pij, A.x);
            A.y = fmaf(w.y, pij, A.y);
            A.z = fmaf(w.z, pij, A.z);
            A.w = fmaf(w.w, pij, A.w);
        }
#pragma unroll
    for (int i = 0; i < NELL; i++) {
        const float4 w = cp[(t++) * CCH];
        A.x = fmaf(w.x, xv[i], A.x);
        A.y = fmaf(w.y, xv[i], A.y);
        A.z = fmaf(w.z, xv[i], A.z);
        A.w = fmaf(w.w, xv[i], A.w);
    }

    if (valid) {
        float* op = out + (size_t)b * (CCH * 4);  // [128 | 384 (c*3+d)]
        op[c] = A.x;
        op[CCH + c * DB + 0] = A.y;
        op[CCH + c * DB + 1] = A.z;
        op[CCH + c * DB + 2] = A.w;
    }
}

// ---------------------------------------------------------------------------
// r7 fallback main (no grouping): one row per block, lane = c.
// ---------------------------------------------------------------------------
__global__ __launch_bounds__(CCH)
void sc_main1(const float* __restrict__ x, const float* __restrict__ y, int E,
              const float* __restrict__ tab, float* __restrict__ out)
{
    const int c = threadIdx.x;
    const int b = blockIdx.x;

    float xv[NELL];
    const float* xp = x + (b * CCH + c) * NELL;
#pragma unroll
    for (int i = 0; i < NELL; i++) xv[i] = xp[i];

    int e = 0;
    for (int q = 0; q < E; q++) if (y[b * E + q] > 0.5f) e = q;

    const float4* cp = (const float4*)tab + (size_t)e * TTOT * CCH + c;
    float4 A = make_float4(0.f, 0.f, 0.f, 0.f);
    int t = 0;
#pragma unroll
    for (int i = 0; i < NELL; i++)
#pragma unroll
        for (int j = i; j < NELL; j++) {
            const float pij = xv[i] * xv[j];
#pragma unroll
            for (int k = j; k < NELL; k++) {
                const float m = pij * xv[k];
                const float4 w = cp[(t++) * CCH];
                A.x = fmaf(w.x, m, A.x);
                A.y = fmaf(w.y, m, A.y);
                A.z = fmaf(w.z, m, A.z);
                A.w = fmaf(w.w, m, A.w);
            }
        }
#pragma unroll
    for (int i = 0; i < NELL; i++)
#pragma unroll
        for (int j = i; j < NELL; j++) {
            const float pij = xv[i] * xv[j];
            const float4 w = cp[(t++) * CCH];
            A.x = fmaf(w.x, pij, A.x);
            A.y = fmaf(w.y, pij, A.y);
            A.z = fmaf(w.z, pij, A.z);
            A.w = fmaf(w.w, pij, A.w);
        }
#pragma unroll
    for (int i = 0; i < NELL; i++) {
        const float4 w = cp[(t++) * CCH];
        A.x = fmaf(w.x, xv[i], A.x);
        A.y = fmaf(w.y, xv[i], A.y);
        A.z = fmaf(w.z, xv[i], A.z);
        A.w = fmaf(w.w, xv[i], A.w);
    }

    float* op = out + b * (CCH * 4);
    op[c] = A.x;
    op[CCH + c * DB + 0] = A.y;
    op[CCH + c * DB + 1] = A.z;
    op[CCH + c * DB + 2] = A.w;
}

// ---------------------------------------------------------------------------
// Last-resort fallback (no ws): r5 direct kernel.
// ---------------------------------------------------------------------------
__global__ __launch_bounds__(CCH)
void sc_direct(const float* __restrict__ x, const float* __restrict__ y, int E,
               const float* __restrict__ U3a, const float* __restrict__ U2a, const float* __restrict__ U1a,
               const float* __restrict__ U3b, const float* __restrict__ U2b, const float* __restrict__ U1b,
               const float* __restrict__ W3a, const float* __restrict__ W2a, const float* __restrict__ W1a,
               const float* __restrict__ W3b, const float* __restrict__ W2b, const float* __restrict__ W1b,
               float* __restrict__ out)
{
    const int c = threadIdx.x;
    const int b = blockIdx.x;

    float xv[NELL];
#pragma unroll
    for (int i = 0; i < NELL; i++) xv[i] = x[(b * CCH + c) * NELL + i];

    int e = 0;
    for (int q = 0; q < E; q++) if (y[b * E + q] > 0.5f) e = q;

    float t3a[P3A] = {}, t3b[DB * P3B] = {};
    float t2a[P2A] = {}, t2b[DB * P2B] = {};
    float t1a = 0.f, t1b[DB] = {};

    for (int i = 0; i < NELL; i++) {
        const float xi = xv[i];
        for (int j = 0; j < NELL; j++) {
            const float xij = xi * xv[j];
            const int ij = i * 9 + j;
#pragma unroll
            for (int p = 0; p < P2A; p++)
                t2a[p] = fmaf(U2a[ij * P2A + p], xij, t2a[p]);
#pragma unroll
            for (int d = 0; d < DB; d++)
#pragma unroll
                for (int p = 0; p < P2B; p++)
                    t2b[d * P2B + p] = fmaf(U2b[(d * 81 + ij) * P2B + p], xij, t2b[d * P2B + p]);
            for (int k = 0; k < NELL; k++) {
                const float m = xij * xv[k];
                const int ijk = ij * 9 + k;
#pragma unroll
                for (int p = 0; p < P3A; p++)
                    t3a[p] = fmaf(U3a[ijk * P3A + p], m, t3a[p]);
#pragma unroll
                for (int d = 0; d < DB; d++)
#pragma unroll
                    for (int p = 0; p < P3B; p++)
                        t3b[d * P3B + p] = fmaf(U3b[(d * 729 + ijk) * P3B + p], m, t3b[d * P3B + p]);
            }
        }
    }
#pragma unroll
    for (int i = 0; i < NELL; i++) {
        t1a = fmaf(U1a[i], xv[i], t1a);
#pragma unroll
        for (int d = 0; d < DB; d++)
            t1b[d] = fmaf(U1b[d * 9 + i], xv[i], t1b[d]);
    }

    float o0 = 0.f;
#pragma unroll
    for (int p = 0; p < P3A; p++) o0 = fmaf(W3a[(e * P3A + p) * CCH + c], t3a[p], o0);
#pragma unroll
    for (int p = 0; p < P2A; p++) o0 = fmaf(W2a[(e * P2A + p) * CCH + c], t2a[p], o0);
    o0 = fmaf(W1a[e * CCH + c], t1a, o0);

    float o1[DB] = {};
#pragma unroll
    for (int p = 0; p < P3B; p++) {
        const float w = W3b[(e * P3B + p) * CCH + c];
#pragma unroll
        for (int d = 0; d < DB; d++) o1[d] = fmaf(w, t3b[d * P3B + p], o1[d]);
    }
#pragma unroll
    for (int p = 0; p < P2B; p++) {
        const float w = W2b[(e * P2B + p) * CCH + c];
#pragma unroll
        for (int d = 0; d < DB; d++) o1[d] = fmaf(w, t2b[d * P2B + p], o1[d]);
    }
    {
        const float w = W1b[e * CCH + c];
#pragma unroll
        for (int d = 0; d < DB; d++) o1[d] = fmaf(w, t1b[d], o1[d]);
    }

    float* op = out + b * (CCH * 4);
    op[c] = o0;
#pragma unroll
    for (int d = 0; d < DB; d++) op[CCH + c * DB + d] = o1[d];
}

extern "C" void kernel_launch(void* const* d_in, const int* in_sizes, int n_in,
                              void* d_out, int out_size, void* d_ws, size_t ws_size,
                              hipStream_t stream)
{
    // ---- order-agnostic classification by element counts (proven r5-r11) ----
    int ix = 0;
    for (int i = 1; i < n_in; i++)
        if (in_sizes[i] > in_sizes[ix]) ix = i;
    int B = in_sizes[ix] / (CCH * NELL);
    bool ok = (n_in == 14) && (B > 0) && (in_sizes[ix] == B * CCH * NELL);

    int iy = -1, E = 0;
    if (ok) {
        for (int i = 0; i < n_in; i++) {
            if (i == ix) continue;
            if (in_sizes[i] % B == 0) {
                int Ec = in_sizes[i] / B;
                if (Ec >= 2 && Ec <= 1024) {
                    if (iy < 0) { iy = i; E = Ec; } else { ok = false; }
                }
            }
        }
        if (iy < 0) ok = false;
    }

    int iU1a = -1, iU2a = -1, iU3a = -1, iU1b = -1, iU2b = -1, iU3b = -1;
    int iW1a = -1, iW1b = -1, iW2a = -1, iW2b = -1, iW3a = -1, iW3b = -1;
    if (ok) {
        for (int i = 0; i < n_in && ok; i++) {
            if (i == ix || i == iy) continue;
            int s = in_sizes[i];
            if      (s == 9 * P1A)        { if (iU1a < 0) iU1a = i; else ok = false; }
            else if (s == 81 * P2A)       { if (iU2a < 0) iU2a = i; else ok = false; }
            else if (s == 729 * P3A)      { if (iU3a < 0) iU3a = i; else ok = false; }
            else if (s == 27 * P1B)       { if (iU1b < 0) iU1b = i; else ok = false; }
            else if (s == 243 * P2B)      { if (iU2b < 0) iU2b = i; else ok = false; }
            else if (s == 2187 * P3B)     { if (iU3b < 0) iU3b = i; else ok = false; }
            else if (s == E * P1A * CCH)  { if (iW1a < 0) iW1a = i; else if (iW1b < 0) iW1b = i; else ok = false; }
            else if (s == E * P2A * CCH)  { if (iW2a < 0) iW2a = i; else ok = false; }
            else if (s == E * P2B * CCH)  { if (iW2b < 0) iW2b = i; else ok = false; }
            else if (s == E * P3A * CCH)  { if (iW3a < 0) iW3a = i; else if (iW3b < 0) iW3b = i; else ok = false; }
            else ok = false;
        }
        if (iU1a < 0 || iU2a < 0 || iU3a < 0 || iU1b < 0 || iU2b < 0 || iU3b < 0 ||
            iW1a < 0 || iW1b < 0 || iW2a < 0 || iW2b < 0 || iW3a < 0 || iW3b < 0)
            ok = false;
    }

    if (!ok) {
        // dict-order fallback
        ix = 0; iy = 1;
        B = in_sizes[0] / (CCH * NELL);
        E = (B > 0) ? in_sizes[1] / B : 1;
        iU1a = 2;  iW1a = 3;  iU2a = 4;  iW2a = 5;  iU3a = 6;  iW3a = 7;
        iU1b = 8;  iW1b = 9;  iU2b = 10; iW2b = 11; iU3b = 12; iW3b = 13;
    }

    const int MAXCH = B / 64 + E + 1;
    const size_t int_bytes = (((size_t)(4 + 3 * MAXCH + B) * sizeof(int)) + 255) & ~(size_t)255;
    const size_t tab_bytes = (size_t)E * TTOT * CCH * 4 * sizeof(float);

    if (ws_size >= int_bytes + tab_bytes && B >= 64) {
        int*   wsi = (int*)d_ws;
        float* tab = (float*)((char*)d_ws + int_bytes);
        hipLaunchKernelGGL(sc_group, dim3(1), dim3(1024), 0, stream,
                           (const float*)d_in[iy], B, E, MAXCH, wsi);
        hipLaunchKernelGGL(sc_prep, dim3(E * TTOT), dim3(CCH), 0, stream,
                           (const float*)d_in[iU3a], (const float*)d_in[iU2a], (const float*)d_in[iU1a],
                           (const float*)d_in[iU3b], (const float*)d_in[iU2b], (const float*)d_in[iU1b],
                           (const float*)d_in[iW3a], (const float*)d_in[iW2a], (const float*)d_in[iW1a],
                           (const float*)d_in[iW3b], (const float*)d_in[iW2b], (const float*)d_in[iW1b],
                           tab);
        hipLaunchKernelGGL(sc_main_chunk, dim3(MAXCH * NCGRP), dim3(256), 0, stream,
                           (const float*)d_in[ix], wsi, MAXCH, tab, (float*)d_out);
    } else if (ws_size >= tab_bytes) {
        float* tab = (float*)d_ws;
        hipLaunchKernelGGL(sc_prep, dim3(E * TTOT), dim3(CCH), 0, stream,
                           (const float*)d_in[iU3a], (const float*)d_in[iU2a], (const float*)d_in[iU1a],
                           (const float*)d_in[iU3b], (const float*)d_in[iU2b], (const float*)d_in[iU1b],
                           (const float*)d_in[iW3a], (const float*)d_in[iW2a], (const float*)d_in[iW1a],
                           (const float*)d_in[iW3b], (const float*)d_in[iW2b], (const float*)d_in[iW1b],
                           tab);
        hipLaunchKernelGGL(sc_main1, dim3(B), dim3(CCH), 0, stream,
                           (const float*)d_in[ix], (const float*)d_in[iy], E,
                           tab, (float*)d_out);
    } else {
        hipLaunchKernelGGL(sc_direct, dim3(B), dim3(CCH), 0, stream,
                           (const float*)d_in[ix], (const float*)d_in[iy], E,
                           (const float*)d_in[iU3a], (const float*)d_in[iU2a], (const float*)d_in[iU1a],
                           (const float*)d_in[iU3b], (const float*)d_in[iU2b], (const float*)d_in[iU1b],
                           (const float*)d_in[iW3a], (const float*)d_in[iW2a], (const float*)d_in[iW1a],
                           (const float*)d_in[iW3b], (const float*)d_in[iW2b], (const float*)d_in[iW1b],
                           (float*)d_out);
    }
}

// Round 13
// 58.978 us; speedup vs baseline: 1.3085x; 1.3085x over previous
//
#include <hip/hip_runtime.h>

#define NELL 9
#define CCH  128
#define DB   3
#define P3A  5
#define P2A  3
#define P1A  1
#define P3B  5
#define P2B  2
#define P1B  1
#define NT3  165
#define NT2  45
#define TTOT (NT3 + NT2 + NELL)   // 219 monomials
#define CPB  4                    // c's per block (1 per wave)
#define NCG  (CCH / CPB)          // 32 c-groups

// ws int-region (ints): [0..3] hdr (0:nchunks), [4..4+MAXCH) chunk_e,
// [4+MAXCH..) chunk_base, [4+2*MAXCH..) chunk_len, [4+3*MAXCH..) perm[B].
// Then (256-aligned) float table.

// ---------------------------------------------------------------------------
// Grouping + 64-row chunk build (r12-proven).
// ---------------------------------------------------------------------------
__global__ __launch_bounds__(1024)
void sc_group(const float* __restrict__ y, int B, int E, int MAXCH,
              int* __restrict__ wsi)
{
    __shared__ int cnt[1024];
    __shared__ int off[1024];
    int* chunk_e    = wsi + 4;
    int* chunk_base = wsi + 4 + MAXCH;
    int* chunk_len  = wsi + 4 + 2 * MAXCH;
    int* perm       = wsi + 4 + 3 * MAXCH;

    for (int i = threadIdx.x; i < E; i += blockDim.x) cnt[i] = 0;
    __syncthreads();
    for (int b = threadIdx.x; b < B; b += blockDim.x) {
        int e = 0;
        for (int q = 0; q < E; q++) if (y[b * E + q] > 0.5f) e = q;
        atomicAdd(&cnt[e], 1);
    }
    __syncthreads();
    if (threadIdx.x == 0) {
        int s = 0;
        for (int e = 0; e < E; e++) { off[e] = s; s += cnt[e]; }
        int nch = 0;
        for (int e = 0; e < E; e++) {
            for (int i = 0; i < cnt[e]; i += 64) {
                chunk_e[nch]    = e;
                chunk_base[nch] = off[e] + i;
                chunk_len[nch]  = (cnt[e] - i < 64) ? (cnt[e] - i) : 64;
                nch++;
            }
        }
        wsi[0] = nch;
    }
    __syncthreads();
    for (int i = threadIdx.x; i < E; i += blockDim.x) cnt[i] = 0;
    __syncthreads();
    for (int b = threadIdx.x; b < B; b += blockDim.x) {
        int e = 0;
        for (int q = 0; q < E; q++) if (y[b * E + q] > 0.5f) e = q;
        int r = atomicAdd(&cnt[e], 1);
        perm[off[e] + r] = b;
    }
}

// ---------------------------------------------------------------------------
// Prep (r7-proven): fused table [e][t][c], float4 over d.
// ---------------------------------------------------------------------------
__global__ __launch_bounds__(CCH)
void sc_prep(const float* __restrict__ U3a, const float* __restrict__ U2a,
             const float* __restrict__ U1a, const float* __restrict__ U3b,
             const float* __restrict__ U2b, const float* __restrict__ U1b,
             const float* __restrict__ W3a, const float* __restrict__ W2a,
             const float* __restrict__ W1a, const float* __restrict__ W3b,
             const float* __restrict__ W2b, const float* __restrict__ W1b,
             float* __restrict__ tab)
{
    const int bt = blockIdx.x;
    const int e = bt / TTOT, t = bt % TTOT;
    const int c = threadIdx.x;

    float v[4] = {0.f, 0.f, 0.f, 0.f};

    if (t < NT3) {
        int idx = t, i = 0, j = 0, k = 0;
        bool done = false;
        for (i = 0; i < NELL && !done; i++)
            for (j = i; j < NELL && !done; j++)
                for (k = j; k < NELL; k++) {
                    if (idx == 0) { done = true; break; }
                    idx--;
                }
        i--; j--;
        const float mult = (i == k) ? 1.f : ((i == j || j == k) ? 3.f : 6.f);
        const int ijk = (i * 9 + j) * 9 + k;
        for (int p = 0; p < P3A; p++)
            v[0] += U3a[ijk * P3A + p] * W3a[(e * P3A + p) * CCH + c];
        for (int d = 0; d < DB; d++)
            for (int p = 0; p < P3B; p++)
                v[1 + d] += U3b[(d * 729 + ijk) * P3B + p] * W3b[(e * P3B + p) * CCH + c];
        for (int d = 0; d < 4; d++) v[d] *= mult;
    } else if (t < NT3 + NT2) {
        int idx = t - NT3, i = 0, j = 0;
        bool done = false;
        for (i = 0; i < NELL && !done; i++)
            for (j = i; j < NELL; j++) {
                if (idx == 0) { done = true; break; }
                idx--;
            }
        i--;
        const float mult = (i == j) ? 1.f : 2.f;
        const int ij = i * 9 + j;
        for (int p = 0; p < P2A; p++)
            v[0] += U2a[ij * P2A + p] * W2a[(e * P2A + p) * CCH + c];
        for (int d = 0; d < DB; d++)
            for (int p = 0; p < P2B; p++)
                v[1 + d] += U2b[(d * 81 + ij) * P2B + p] * W2b[(e * P2B + p) * CCH + c];
        for (int d = 0; d < 4; d++) v[d] *= mult;
    } else {
        const int i = t - NT3 - NT2;
        v[0] = U1a[i] * W1a[e * CCH + c];
        for (int d = 0; d < DB; d++)
            v[1 + d] = U1b[d * 9 + i] * W1b[e * CCH + c];
    }

    ((float4*)tab)[(size_t)bt * CCH + c] = make_float4(v[0], v[1], v[2], v[3]);
}

// ---------------------------------------------------------------------------
// Pair contraction core: w from LDS broadcast; SAME shares one read.
// Per-row t-order/FMA order = r7 verbatim (bit-identical results).
// ---------------------------------------------------------------------------
template <bool SAME>
__device__ __forceinline__ void core2(const float4* __restrict__ t0,
                                      const float4* __restrict__ t1,
                                      const float* xv0, const float* xv1,
                                      float4& A0, float4& A1)
{
    int t = 0;
#pragma unroll
    for (int i = 0; i < NELL; i++)
#pragma unroll
        for (int j = i; j < NELL; j++) {
            const float p0 = xv0[i] * xv0[j];
            const float p1 = xv1[i] * xv1[j];
#pragma unroll
            for (int k = j; k < NELL; k++) {
                const float m0 = p0 * xv0[k];
                const float m1 = p1 * xv1[k];
                const float4 w0 = t0[t * CPB];
                const float4 w1 = SAME ? w0 : t1[t * CPB];
                A0.x = fmaf(w0.x, m0, A0.x);
                A0.y = fmaf(w0.y, m0, A0.y);
                A0.z = fmaf(w0.z, m0, A0.z);
                A0.w = fmaf(w0.w, m0, A0.w);
                A1.x = fmaf(w1.x, m1, A1.x);
                A1.y = fmaf(w1.y, m1, A1.y);
                A1.z = fmaf(w1.z, m1, A1.z);
                A1.w = fmaf(w1.w, m1, A1.w);
                t++;
            }
        }
#pragma unroll
    for (int i = 0; i < NELL; i++)
#pragma unroll
        for (int j = i; j < NELL; j++) {
            const float p0 = xv0[i] * xv0[j];
            const float p1 = xv1[i] * xv1[j];
            const float4 w0 = t0[t * CPB];
            const float4 w1 = SAME ? w0 : t1[t * CPB];
            A0.x = fmaf(w0.x, p0, A0.x);
            A0.y = fmaf(w0.y, p0, A0.y);
            A0.z = fmaf(w0.z, p0, A0.z);
            A0.w = fmaf(w0.w, p0, A0.w);
            A1.x = fmaf(w1.x, p1, A1.x);
            A1.y = fmaf(w1.y, p1, A1.y);
            A1.z = fmaf(w1.z, p1, A1.z);
            A1.w = fmaf(w1.w, p1, A1.w);
            t++;
        }
#pragma unroll
    for (int i = 0; i < NELL; i++) {
        const float4 w0 = t0[t * CPB];
        const float4 w1 = SAME ? w0 : t1[t * CPB];
        A0.x = fmaf(w0.x, xv0[i], A0.x);
        A0.y = fmaf(w0.y, xv0[i], A0.y);
        A0.z = fmaf(w0.z, xv0[i], A0.z);
        A0.w = fmaf(w0.w, xv0[i], A0.w);
        A1.x = fmaf(w1.x, xv1[i], A1.x);
        A1.y = fmaf(w1.y, xv1[i], A1.y);
        A1.z = fmaf(w1.z, xv1[i], A1.z);
        A1.w = fmaf(w1.w, xv1[i], A1.w);
        t++;
    }
}

// ---------------------------------------------------------------------------
// Main: block = 4 waves x 64 lanes; lane = row, wave-uniform c (cg*4+wv).
// Block handles a PAIR of 64-row chunks; per-(e,4c) table tiles staged in LDS;
// coefficient reads are broadcast ds_read_b128, each feeding 8 FMAs.
// ---------------------------------------------------------------------------
__global__ __launch_bounds__(256)
void sc_main_pair(const float* __restrict__ x, const int* __restrict__ wsi,
                  int MAXCH, const float* __restrict__ tab,
                  float* __restrict__ out)
{
    __shared__ float4 tile[2][TTOT][CPB];   // 28 KB

    const int pair = blockIdx.x >> 5;       // / NCG
    const int cg   = blockIdx.x & (NCG - 1);
    const int nch  = wsi[0];
    const int h0   = pair * 2;
    if (h0 >= nch) return;
    const int h1 = (h0 + 1 < nch) ? h0 + 1 : h0;

    const int e0    = wsi[4 + h0];
    const int e1    = wsi[4 + h1];
    const int base0 = wsi[4 + MAXCH + h0];
    const int base1 = wsi[4 + MAXCH + h1];
    const int len0  = wsi[4 + 2 * MAXCH + h0];
    const int len1  = wsi[4 + 2 * MAXCH + h1];
    const int* perm = wsi + 4 + 3 * MAXCH;

    // stage both tiles (coalesced-ish: 4 consecutive float4 per t)
    const float4* tb = (const float4*)tab;
    for (int idx = threadIdx.x; idx < 2 * TTOT * CPB; idx += 256) {
        const int h  = idx / (TTOT * CPB);
        const int r  = idx - h * (TTOT * CPB);
        const int t  = r >> 2;
        const int cl = r & 3;
        const int e  = h ? e1 : e0;
        tile[h][t][cl] = tb[((size_t)e * TTOT + t) * CCH + cg * CPB + cl];
    }
    __syncthreads();

    const int wv   = threadIdx.x >> 6;      // 0..3 -> c_local
    const int lane = threadIdx.x & 63;
    const int c    = cg * CPB + wv;

    const bool v0 = (lane < len0);
    const bool v1 = (lane < len1);
    const int b0 = perm[base0 + (v0 ? lane : 0)];
    const int b1 = perm[base1 + (v1 ? lane : 0)];

    float xv0[NELL], xv1[NELL];
    const float* xp0 = x + ((size_t)b0 * CCH + c) * NELL;
    const float* xp1 = x + ((size_t)b1 * CCH + c) * NELL;
#pragma unroll
    for (int i = 0; i < NELL; i++) { xv0[i] = xp0[i]; xv1[i] = xp1[i]; }

    float4 A0 = make_float4(0.f, 0.f, 0.f, 0.f);
    float4 A1 = make_float4(0.f, 0.f, 0.f, 0.f);

    const float4* t0 = &tile[0][0][wv];
    const float4* t1 = &tile[1][0][wv];
    if (e0 == e1) core2<true>(t0, t1, xv0, xv1, A0, A1);
    else          core2<false>(t0, t1, xv0, xv1, A0, A1);

    if (v0) {
        float* op = out + (size_t)b0 * (CCH * 4);
        op[c] = A0.x;
        op[CCH + c * DB + 0] = A0.y;
        op[CCH + c * DB + 1] = A0.z;
        op[CCH + c * DB + 2] = A0.w;
    }
    if (v1 && h1 != h0) {
        float* op = out + (size_t)b1 * (CCH * 4);
        op[c] = A1.x;
        op[CCH + c * DB + 0] = A1.y;
        op[CCH + c * DB + 1] = A1.z;
        op[CCH + c * DB + 2] = A1.w;
    }
}

// ---------------------------------------------------------------------------
// r7 fallback main (no grouping): one row per block, lane = c.
// ---------------------------------------------------------------------------
__global__ __launch_bounds__(CCH)
void sc_main1(const float* __restrict__ x, const float* __restrict__ y, int E,
              const float* __restrict__ tab, float* __restrict__ out)
{
    const int c = threadIdx.x;
    const int b = blockIdx.x;

    float xv[NELL];
    const float* xp = x + (b * CCH + c) * NELL;
#pragma unroll
    for (int i = 0; i < NELL; i++) xv[i] = xp[i];

    int e = 0;
    for (int q = 0; q < E; q++) if (y[b * E + q] > 0.5f) e = q;

    const float4* cp = (const float4*)tab + (size_t)e * TTOT * CCH + c;
    float4 A = make_float4(0.f, 0.f, 0.f, 0.f);
    int t = 0;
#pragma unroll
    for (int i = 0; i < NELL; i++)
#pragma unroll
        for (int j = i; j < NELL; j++) {
            const float pij = xv[i] * xv[j];
#pragma unroll
            for (int k = j; k < NELL; k++) {
                const float m = pij * xv[k];
                const float4 w = cp[(t++) * CCH];
                A.x = fmaf(w.x, m, A.x);
                A.y = fmaf(w.y, m, A.y);
                A.z = fmaf(w.z, m, A.z);
                A.w = fmaf(w.w, m, A.w);
            }
        }
#pragma unroll
    for (int i = 0; i < NELL; i++)
#pragma unroll
        for (int j = i; j < NELL; j++) {
            const float pij = xv[i] * xv[j];
            const float4 w = cp[(t++) * CCH];
            A.x = fmaf(w.x, pij, A.x);
            A.y = fmaf(w.y, pij, A.y);
            A.z = fmaf(w.z, pij, A.z);
            A.w = fmaf(w.w, pij, A.w);
        }
#pragma unroll
    for (int i = 0; i < NELL; i++) {
        const float4 w = cp[(t++) * CCH];
        A.x = fmaf(w.x, xv[i], A.x);
        A.y = fmaf(w.y, xv[i], A.y);
        A.z = fmaf(w.z, xv[i], A.z);
        A.w = fmaf(w.w, xv[i], A.w);
    }

    float* op = out + b * (CCH * 4);
    op[c] = A.x;
    op[CCH + c * DB + 0] = A.y;
    op[CCH + c * DB + 1] = A.z;
    op[CCH + c * DB + 2] = A.w;
}

// ---------------------------------------------------------------------------
// Last-resort fallback (no ws): r5 direct kernel.
// ---------------------------------------------------------------------------
__global__ __launch_bounds__(CCH)
void sc_direct(const float* __restrict__ x, const float* __restrict__ y, int E,
               const float* __restrict__ U3a, const float* __restrict__ U2a, const float* __restrict__ U1a,
               const float* __restrict__ U3b, const float* __restrict__ U2b, const float* __restrict__ U1b,
               const float* __restrict__ W3a, const float* __restrict__ W2a, const float* __restrict__ W1a,
               const float* __restrict__ W3b, const float* __restrict__ W2b, const float* __restrict__ W1b,
               float* __restrict__ out)
{
    const int c = threadIdx.x;
    const int b = blockIdx.x;

    float xv[NELL];
#pragma unroll
    for (int i = 0; i < NELL; i++) xv[i] = x[(b * CCH + c) * NELL + i];

    int e = 0;
    for (int q = 0; q < E; q++) if (y[b * E + q] > 0.5f) e = q;

    float t3a[P3A] = {}, t3b[DB * P3B] = {};
    float t2a[P2A] = {}, t2b[DB * P2B] = {};
    float t1a = 0.f, t1b[DB] = {};

    for (int i = 0; i < NELL; i++) {
        const float xi = xv[i];
        for (int j = 0; j < NELL; j++) {
            const float xij = xi * xv[j];
            const int ij = i * 9 + j;
#pragma unroll
            for (int p = 0; p < P2A; p++)
                t2a[p] = fmaf(U2a[ij * P2A + p], xij, t2a[p]);
#pragma unroll
            for (int d = 0; d < DB; d++)
#pragma unroll
                for (int p = 0; p < P2B; p++)
                    t2b[d * P2B + p] = fmaf(U2b[(d * 81 + ij) * P2B + p], xij, t2b[d * P2B + p]);
            for (int k = 0; k < NELL; k++) {
                const float m = xij * xv[k];
                const int ijk = ij * 9 + k;
#pragma unroll
                for (int p = 0; p < P3A; p++)
                    t3a[p] = fmaf(U3a[ijk * P3A + p], m, t3a[p]);
#pragma unroll
                for (int d = 0; d < DB; d++)
#pragma unroll
                    for (int p = 0; p < P3B; p++)
                        t3b[d * P3B + p] = fmaf(U3b[(d * 729 + ijk) * P3B + p], m, t3b[d * P3B + p]);
            }
        }
    }
#pragma unroll
    for (int i = 0; i < NELL; i++) {
        t1a = fmaf(U1a[i], xv[i], t1a);
#pragma unroll
        for (int d = 0; d < DB; d++)
            t1b[d] = fmaf(U1b[d * 9 + i], xv[i], t1b[d]);
    }

    float o0 = 0.f;
#pragma unroll
    for (int p = 0; p < P3A; p++) o0 = fmaf(W3a[(e * P3A + p) * CCH + c], t3a[p], o0);
#pragma unroll
    for (int p = 0; p < P2A; p++) o0 = fmaf(W2a[(e * P2A + p) * CCH + c], t2a[p], o0);
    o0 = fmaf(W1a[e * CCH + c], t1a, o0);

    float o1[DB] = {};
#pragma unroll
    for (int p = 0; p < P3B; p++) {
        const float w = W3b[(e * P3B + p) * CCH + c];
#pragma unroll
        for (int d = 0; d < DB; d++) o1[d] = fmaf(w, t3b[d * P3B + p], o1[d]);
    }
#pragma unroll
    for (int p = 0; p < P2B; p++) {
        const float w = W2b[(e * P2B + p) * CCH + c];
#pragma unroll
        for (int d = 0; d < DB; d++) o1[d] = fmaf(w, t2b[d * P2B + p], o1[d]);
    }
    {
        const float w = W1b[e * CCH + c];
#pragma unroll
        for (int d = 0; d < DB; d++) o1[d] = fmaf(w, t1b[d], o1[d]);
    }

    float* op = out + b * (CCH * 4);
    op[c] = o0;
#pragma unroll
    for (int d = 0; d < DB; d++) op[CCH + c * DB + d] = o1[d];
}

extern "C" void kernel_launch(void* const* d_in, const int* in_sizes, int n_in,
                              void* d_out, int out_size, void* d_ws, size_t ws_size,
                              hipStream_t stream)
{
    // ---- order-agnostic classification by element counts (proven r5-r12) ----
    int ix = 0;
    for (int i = 1; i < n_in; i++)
        if (in_sizes[i] > in_sizes[ix]) ix = i;
    int B = in_sizes[ix] / (CCH * NELL);
    bool ok = (n_in == 14) && (B > 0) && (in_sizes[ix] == B * CCH * NELL);

    int iy = -1, E = 0;
    if (ok) {
        for (int i = 0; i < n_in; i++) {
            if (i == ix) continue;
            if (in_sizes[i] % B == 0) {
                int Ec = in_sizes[i] / B;
                if (Ec >= 2 && Ec <= 1024) {
                    if (iy < 0) { iy = i; E = Ec; } else { ok = false; }
                }
            }
        }
        if (iy < 0) ok = false;
    }

    int iU1a = -1, iU2a = -1, iU3a = -1, iU1b = -1, iU2b = -1, iU3b = -1;
    int iW1a = -1, iW1b = -1, iW2a = -1, iW2b = -1, iW3a = -1, iW3b = -1;
    if (ok) {
        for (int i = 0; i < n_in && ok; i++) {
            if (i == ix || i == iy) continue;
            int s = in_sizes[i];
            if      (s == 9 * P1A)        { if (iU1a < 0) iU1a = i; else ok = false; }
            else if (s == 81 * P2A)       { if (iU2a < 0) iU2a = i; else ok = false; }
            else if (s == 729 * P3A)      { if (iU3a < 0) iU3a = i; else ok = false; }
            else if (s == 27 * P1B)       { if (iU1b < 0) iU1b = i; else ok = false; }
            else if (s == 243 * P2B)      { if (iU2b < 0) iU2b = i; else ok = false; }
            else if (s == 2187 * P3B)     { if (iU3b < 0) iU3b = i; else ok = false; }
            else if (s == E * P1A * CCH)  { if (iW1a < 0) iW1a = i; else if (iW1b < 0) iW1b = i; else ok = false; }
            else if (s == E * P2A * CCH)  { if (iW2a < 0) iW2a = i; else ok = false; }
            else if (s == E * P2B * CCH)  { if (iW2b < 0) iW2b = i; else ok = false; }
            else if (s == E * P3A * CCH)  { if (iW3a < 0) iW3a = i; else if (iW3b < 0) iW3b = i; else ok = false; }
            else ok = false;
        }
        if (iU1a < 0 || iU2a < 0 || iU3a < 0 || iU1b < 0 || iU2b < 0 || iU3b < 0 ||
            iW1a < 0 || iW1b < 0 || iW2a < 0 || iW2b < 0 || iW3a < 0 || iW3b < 0)
            ok = false;
    }

    if (!ok) {
        // dict-order fallback
        ix = 0; iy = 1;
        B = in_sizes[0] / (CCH * NELL);
        E = (B > 0) ? in_sizes[1] / B : 1;
        iU1a = 2;  iW1a = 3;  iU2a = 4;  iW2a = 5;  iU3a = 6;  iW3a = 7;
        iU1b = 8;  iW1b = 9;  iU2b = 10; iW2b = 11; iU3b = 12; iW3b = 13;
    }

    const int MAXCH = B / 64 + E + 1;
    const size_t int_bytes = (((size_t)(4 + 3 * MAXCH + B) * sizeof(int)) + 255) & ~(size_t)255;
    const size_t tab_bytes = (size_t)E * TTOT * CCH * 4 * sizeof(float);

    if (ws_size >= int_bytes + tab_bytes && B >= 64) {
        int*   wsi = (int*)d_ws;
        float* tab = (float*)((char*)d_ws + int_bytes);
        hipLaunchKernelGGL(sc_group, dim3(1), dim3(1024), 0, stream,
                           (const float*)d_in[iy], B, E, MAXCH, wsi);
        hipLaunchKernelGGL(sc_prep, dim3(E * TTOT), dim3(CCH), 0, stream,
                           (const float*)d_in[iU3a], (const float*)d_in[iU2a], (const float*)d_in[iU1a],
                           (const float*)d_in[iU3b], (const float*)d_in[iU2b], (const float*)d_in[iU1b],
                           (const float*)d_in[iW3a], (const float*)d_in[iW2a], (const float*)d_in[iW1a],
                           (const float*)d_in[iW3b], (const float*)d_in[iW2b], (const float*)d_in[iW1b],
                           tab);
        const int npairs = (MAXCH + 1) / 2;
        hipLaunchKernelGGL(sc_main_pair, dim3(npairs * NCG), dim3(256), 0, stream,
                           (const float*)d_in[ix], wsi, MAXCH, tab, (float*)d_out);
    } else if (ws_size >= tab_bytes) {
        float* tab = (float*)d_ws;
        hipLaunchKernelGGL(sc_prep, dim3(E * TTOT), dim3(CCH), 0, stream,
                           (const float*)d_in[iU3a], (const float*)d_in[iU2a], (const float*)d_in[iU1a],
                           (const float*)d_in[iU3b], (const float*)d_in[iU2b], (const float*)d_in[iU1b],
                           (const float*)d_in[iW3a], (const float*)d_in[iW2a], (const float*)d_in[iW1a],
                           (const float*)d_in[iW3b], (const float*)d_in[iW2b], (const float*)d_in[iW1b],
                           tab);
        hipLaunchKernelGGL(sc_main1, dim3(B), dim3(CCH), 0, stream,
                           (const float*)d_in[ix], (const float*)d_in[iy], E,
                           tab, (float*)d_out);
    } else {
        hipLaunchKernelGGL(sc_direct, dim3(B), dim3(CCH), 0, stream,
                           (const float*)d_in[ix], (const float*)d_in[iy], E,
                           (const float*)d_in[iU3a], (const float*)d_in[iU2a], (const float*)d_in[iU1a],
                           (const float*)d_in[iU3b], (const float*)d_in[iU2b], (const float*)d_in[iU1b],
                           (const float*)d_in[iW3a], (const float*)d_in[iW2a], (const float*)d_in[iW1a],
                           (const float*)d_in[iW3b], (const float*)d_in[iW2b], (const float*)d_in[iW1b],
                           (float*)d_out);
    }
}